// Round 7
// baseline (200.827 us; speedup 1.0000x reference)
//
#include <hip/hip_runtime.h>
#include <hip/hip_bf16.h>

// Problem constants (fixed by setup_inputs)
#define NXc 16384
#define DHc 128          // d_hidden
#define DLc 64           // d_latent
#define Kc  3            // neighbor radius
#define Wc  7            // 2k+1 offsets
#define Pc  32           // points per block
#define NTc 256          // threads per block
#define HALO 38          // Pc + 2*Kc
#define RB  272          // bf16 activation LDS row stride (128*2 + 16 pad)

typedef __attribute__((ext_vector_type(8))) short short8;   // 8 bf16 = one MFMA A/B fragment
typedef __attribute__((ext_vector_type(4))) float f32x4;    // MFMA accumulator
typedef __attribute__((ext_vector_type(2))) float f32x2;    // packed fp32 (v_pk_* target)

// LDS layout (bytes). c registerized. H2 overlays GN (dead after C).
#define OFF_U  0                    // 38 fp32 (pad to 160)
#define OFF_X  160                  // -> 320
#define OFF_GN 320                  // bf16 [32][RB] = 8704 -> 9024
#define OFF_H2 OFF_GN               // alias (gn dead after C)
#define OFF_S  9024                 // bf16 [32][RB] = 8704 -> 17728
#define OFF_HC 17728                // bf16 [32][RB] = 8704 -> 26432
#define SMEM_BYTES 26432            // 6 blocks/CU

// ws layout in bf16 elements. Fragment f=(nt*4+kt), lane l, j:
// element W[kt*32 + (l>>4)*8 + j][nt*16 + (l&15)] at base + f*512 + l*8 + j.
// Used as the MFMA *A* operand => D = (act@W)^T (register-transpose trick).
#define WS_NW2 0        // 128x64
#define WS_EW2 8192     // 128x64
#define WS_CW1 16384    // 128x128
#define WS_CW2 32768    // 128x64
#define WS_TOTAL 40960

#if __has_builtin(__builtin_amdgcn_exp2f)
#define EXP2F(x) __builtin_amdgcn_exp2f(x)
#else
#define EXP2F(x) exp2f(x)
#endif
#if __has_builtin(__builtin_amdgcn_rcpf)
#define RCPF(x) __builtin_amdgcn_rcpf(x)
#else
#define RCPF(x) (1.0f / (x))
#endif

// tanh-form GELU via sigmoid: gelu(x) = x / (1 + exp2(x*(c0 + c1*x^2)))
#define GC0 -2.30220838f
#define GC1 -0.10294325f

__device__ __forceinline__ f32x2 vfma(f32x2 a, f32x2 b, f32x2 c) {
    return __builtin_elementwise_fma(a, b, c);
}
__device__ __forceinline__ f32x2 splat2(float s) { f32x2 v = {s, s}; return v; }

// Paired gelu on a packed float2: one rcp for two gelus (exact pairing identity).
// Inputs clamped at -8 (gelu(-8) ~ 0) so exp2 can't overflow.
__device__ __forceinline__ f32x2 gelu2v(f32x2 xv) {
    xv = __builtin_elementwise_max(xv, splat2(-8.0f));
    f32x2 z = xv * vfma(splat2(GC1), xv * xv, splat2(GC0));
    f32x2 t;
    t.x = EXP2F(z.x);
    t.y = EXP2F(z.y);
    t = t + splat2(1.0f);
    float rr = RCPF(t.x * t.y);
    f32x2 ts = {t.y, t.x};          // swap = register renaming, free
    return xv * ts * splat2(rr);
}

// acc += gelu(xv) elementwise, one shared rcp. Edge args bounded (|x|<~3) -> no clamp.
__device__ __forceinline__ void gelu2_accv(f32x2 xv, f32x2& acc) {
    f32x2 z = xv * vfma(splat2(GC1), xv * xv, splat2(GC0));
    f32x2 t;
    t.x = EXP2F(z.x);
    t.y = EXP2F(z.y);
    t = t + splat2(1.0f);
    float rr = RCPF(t.x * t.y);
    f32x2 ts = {t.y, t.x};
    acc = vfma(xv * ts, splat2(rr), acc);
}

// bf16 pair pack: HW v_cvt_pk_bf16_f32 (gfx950) when available, else branchless RNE.
#if __has_builtin(__builtin_amdgcn_cvt_pk_bf16_f32)
typedef __attribute__((ext_vector_type(2))) __bf16 bf16x2_t;
__device__ __forceinline__ unsigned pack_bf16(float a, float b) {
    bf16x2_t v = __builtin_amdgcn_cvt_pk_bf16_f32(a, b);   // lo = src0, hi = src1
    unsigned r; __builtin_memcpy(&r, &v, 4); return r;
}
#else
__device__ __forceinline__ unsigned bf16rne(float a) {
    unsigned u;
    __builtin_memcpy(&u, &a, 4);
    return u + 0x7FFFu + ((u >> 16) & 1u);
}
__device__ __forceinline__ unsigned pack_bf16(float a, float b) {
    return (bf16rne(a) >> 16) | (bf16rne(b) & 0xFFFF0000u);
}
#endif
__device__ __forceinline__ void store_bf16x4(void* p, float a, float b, float c, float d) {
    uint2 u;
    u.x = pack_bf16(a, b);
    u.y = pack_bf16(c, d);
    *(uint2*)p = u;
}

// ---- prep: fp32 weights -> bf16 MFMA fragments in ws ----
__global__ void pack_weights(const float* __restrict__ nw2, const float* __restrict__ ew2,
                             const float* __restrict__ cw1, const float* __restrict__ cw2,
                             __hip_bfloat16* __restrict__ ws)
{
    int idx = blockIdx.x * 256 + threadIdx.x;     // 0 .. 40959
    const float* src;
    int N, base, e;
    if (idx < 8192)       { src = nw2; N = 64;  base = WS_NW2; e = idx; }
    else if (idx < 16384) { src = ew2; N = 64;  base = WS_EW2; e = idx - 8192; }
    else if (idx < 32768) { src = cw1; N = 128; base = WS_CW1; e = idx - 16384; }
    else                  { src = cw2; N = 64;  base = WS_CW2; e = idx - 32768; }
    int f = e >> 9, l = (e >> 3) & 63, j = e & 7;
    int nt = f >> 2, kt = f & 3;
    int k = kt * 32 + (l >> 4) * 8 + j;
    int n = nt * 16 + (l & 15);
    ws[base + e] = __float2bfloat16(src[k * N + n]);
}

__global__ __launch_bounds__(NTc, 6)
void lifting_mfma(const float* __restrict__ u0, const float* __restrict__ x,
                  const float* __restrict__ nw1, const float* __restrict__ nb1,
                  const float* __restrict__ nb2, const float* __restrict__ eb1,
                  const float* __restrict__ eb2, const float* __restrict__ cb1,
                  const float* __restrict__ cb2, const float* __restrict__ ew1,
                  const short8* __restrict__ wsv, float* __restrict__ out)
{
    __shared__ char sm[SMEM_BYTES];
    float* s_u = (float*)(sm + OFF_U);
    float* s_x = (float*)(sm + OFF_X);

    const int tid   = threadIdx.x;
    const int wave  = tid >> 6;
    const int lane  = tid & 63;
    const int quad  = lane >> 4;
    const int l15   = lane & 15;
    const int tiles = NXc / Pc;
    const int b     = blockIdx.x / tiles;
    const int i0    = (blockIdx.x % tiles) * Pc;
    const float* ub = u0 + (size_t)b * NXc;
    const float* xb = x  + (size_t)b * NXc;

    // ---- Phase 0: halo load with clamp ----
    if (tid < HALO) {
        int i = i0 - Kc + tid;
        i = i < 0 ? 0 : (i >= NXc ? NXc - 1 : i);
        s_u[tid] = ub[i];
        s_x[tid] = xb[i];
    }
    __syncthreads();

    // ---- Phase B (fused, packed-fp32): thread owns dim-quad jq for 4 CONSECUTIVE
    //      points; 10-row c-window in registers as f32x2 pairs. ----
    {
        const int jq = tid & 31;           // dim quad 0..31
        const int pbase = (tid >> 5) * 4;  // points pbase..pbase+3
        const int j0 = jq * 4;
        const f32x2 w0l = *(const f32x2*)(nw1 + j0),           w0h = *(const f32x2*)(nw1 + j0 + 2);
        const f32x2 w1l = *(const f32x2*)(nw1 + DHc + j0),     w1h = *(const f32x2*)(nw1 + DHc + j0 + 2);
        const f32x2 nbl = *(const f32x2*)(nb1 + j0),           nbh = *(const f32x2*)(nb1 + j0 + 2);
        const f32x2 e0l = *(const f32x2*)(ew1 + j0),           e0h = *(const f32x2*)(ew1 + j0 + 2);
        const f32x2 e1l = *(const f32x2*)(ew1 + DHc + j0),     e1h = *(const f32x2*)(ew1 + DHc + j0 + 2);
        const f32x2 e2l = *(const f32x2*)(ew1 + 2 * DHc + j0), e2h = *(const f32x2*)(ew1 + 2 * DHc + j0 + 2);
        const f32x2 bel = *(const f32x2*)(eb1 + j0),           beh = *(const f32x2*)(eb1 + j0 + 2);

        float su[10], sx[10];
        #pragma unroll
        for (int r = 0; r < 10; ++r) {
            su[r] = s_u[pbase + r];        // halo rows pbase .. pbase+9
            sx[r] = s_x[pbase + r];
        }

        f32x2 cwl[10], cwh[10];            // c_j window, packed fp32
        #pragma unroll
        for (int r = 0; r < 10; ++r) {
            f32x2 uv = splat2(su[r]), xv = splat2(sx[r]);
            cwl[r] = vfma(uv, e1l, xv * e2l);
            cwh[r] = vfma(uv, e1h, xv * e2h);
        }

        #pragma unroll
        for (int r0 = 0; r0 < 4; ++r0) {
            const int p = pbase + r0;
            const f32x2 uv = splat2(su[r0 + 3]), xv = splat2(sx[r0 + 3]);

            // node MLP first layer + gelu -> gn (bf16)
            f32x2 gl = gelu2v(vfma(uv, w0l, vfma(xv, w1l, nbl)));
            f32x2 gh = gelu2v(vfma(uv, w0h, vfma(xv, w1h, nbh)));
            store_bf16x4(sm + OFF_GN + p * RB + j0 * 2, gl.x, gl.y, gh.x, gh.y);

            // edge: a_i = u_i*W0 - x_i*W2 + b1 ; 7-offset gelu-sum from register window
            f32x2 al = vfma(uv, e0l, bel - xv * e2l);
            f32x2 ah = vfma(uv, e0h, beh - xv * e2h);
            f32x2 accl = {0.f, 0.f}, acch = {0.f, 0.f};
            #pragma unroll
            for (int o = 0; o < Wc; ++o) {
                gelu2_accv(al + cwl[r0 + o], accl);
                gelu2_accv(ah + cwh[r0 + o], acch);
            }
            store_bf16x4(sm + OFF_S + p * RB + j0 * 2, accl.x, accl.y, acch.x, acch.y);
        }
    }
    __syncthreads();

    // ---- Phase C (MFMA, W as A-operand): D = (act@W)^T -> col=point, rows=4 consecutive features
    //      hcat[:,0:64] = gn@nw2 + nb2 ; hcat[:,64:128] = s@ew2 + 7*eb2 ----
    {
        const int mt = wave & 1, mat = wave >> 1;
        const int rowbase = mt * 16;
        const int aoff = mat ? OFF_S : OFF_GN;
        const short8* Bmat = wsv + (mat ? (WS_EW2 >> 3) : (WS_NW2 >> 3));
        f32x4 acc[4] = {{0,0,0,0},{0,0,0,0},{0,0,0,0},{0,0,0,0}};
        #pragma unroll
        for (int kt = 0; kt < 4; ++kt) {
            short8 af = *(const short8*)(sm + aoff + (rowbase + l15) * RB + kt * 64 + quad * 16);
            #pragma unroll
            for (int nt = 0; nt < 4; ++nt) {
                short8 wf = Bmat[(nt * 4 + kt) * 64 + lane];
                acc[nt] = __builtin_amdgcn_mfma_f32_16x16x32_bf16(wf, af, acc[nt], 0, 0, 0);
            }
        }
        const float* bias = mat ? eb2 : nb2;
        const float bscale = mat ? 7.f : 1.f;
        const int colhalf = mat ? DLc : 0;
        const int p = rowbase + l15;          // point this lane owns
        #pragma unroll
        for (int nt = 0; nt < 4; ++nt) {
            float4 bv = ((const float4*)bias)[nt * 4 + quad];   // features nt*16+quad*4 ..+3
            store_bf16x4(sm + OFF_HC + p * RB + (colhalf + nt * 16 + quad * 4) * 2,
                         fmaf(bscale, bv.x, acc[nt][0]),
                         fmaf(bscale, bv.y, acc[nt][1]),
                         fmaf(bscale, bv.z, acc[nt][2]),
                         fmaf(bscale, bv.w, acc[nt][3]));
        }
    }
    __syncthreads();

    // ---- Phase D (MFMA): h2 = gelu(hcat @ cw1 + cb1), feature halves across wave pairs ----
    {
        const int mt = wave & 1, nh = wave >> 1;
        const int rowbase = mt * 16;
        const short8* Bmat = wsv + (WS_CW1 >> 3);
        f32x4 acc[4] = {{0,0,0,0},{0,0,0,0},{0,0,0,0},{0,0,0,0}};
        #pragma unroll
        for (int kt = 0; kt < 4; ++kt) {
            short8 af = *(const short8*)(sm + OFF_HC + (rowbase + l15) * RB + kt * 64 + quad * 16);
            #pragma unroll
            for (int t = 0; t < 4; ++t) {
                int nt = nh * 4 + t;
                short8 wf = Bmat[(nt * 4 + kt) * 64 + lane];
                acc[t] = __builtin_amdgcn_mfma_f32_16x16x32_bf16(wf, af, acc[t], 0, 0, 0);
            }
        }
        const int p = rowbase + l15;
        #pragma unroll
        for (int t = 0; t < 4; ++t) {
            int nbase = (nh * 4 + t) * 16 + quad * 4;
            float4 cb = ((const float4*)cb1)[nbase >> 2];
            f32x2 pl = {acc[t][0] + cb.x, acc[t][1] + cb.y};
            f32x2 ph = {acc[t][2] + cb.z, acc[t][3] + cb.w};
            f32x2 hl = gelu2v(pl), hh = gelu2v(ph);
            store_bf16x4(sm + OFF_H2 + p * RB + nbase * 2, hl.x, hl.y, hh.x, hh.y);
        }
    }
    __syncthreads();

    // ---- Phase E (MFMA): out = h2 @ cw2 + cb2, float4 straight to global ----
    {
        const int mt = wave & 1, nh = wave >> 1;
        const int rowbase = mt * 16;
        const short8* Bmat = wsv + (WS_CW2 >> 3);
        f32x4 acc[2] = {{0,0,0,0},{0,0,0,0}};
        #pragma unroll
        for (int kt = 0; kt < 4; ++kt) {
            short8 af = *(const short8*)(sm + OFF_H2 + (rowbase + l15) * RB + kt * 64 + quad * 16);
            #pragma unroll
            for (int t = 0; t < 2; ++t) {
                int nt = nh * 2 + t;
                short8 wf = Bmat[(nt * 4 + kt) * 64 + lane];
                acc[t] = __builtin_amdgcn_mfma_f32_16x16x32_bf16(wf, af, acc[t], 0, 0, 0);
            }
        }
        const int p = rowbase + l15;
        float* outb = out + ((size_t)b * NXc + i0 + p) * DLc;
        #pragma unroll
        for (int t = 0; t < 2; ++t) {
            int nbase = (nh * 2 + t) * 16 + quad * 4;
            float4 cb = ((const float4*)cb2)[nbase >> 2];
            float4 v;
            v.x = acc[t][0] + cb.x;
            v.y = acc[t][1] + cb.y;
            v.z = acc[t][2] + cb.z;
            v.w = acc[t][3] + cb.w;
            *(float4*)(outb + nbase) = v;
        }
    }
}

extern "C" void kernel_launch(void* const* d_in, const int* in_sizes, int n_in,
                              void* d_out, int out_size, void* d_ws, size_t ws_size,
                              hipStream_t stream) {
    const float* u0  = (const float*)d_in[0];
    const float* x   = (const float*)d_in[1];
    const float* nw1 = (const float*)d_in[2];
    const float* nb1 = (const float*)d_in[3];
    const float* nw2 = (const float*)d_in[4];
    const float* nb2 = (const float*)d_in[5];
    const float* ew1 = (const float*)d_in[6];
    const float* eb1 = (const float*)d_in[7];
    const float* ew2 = (const float*)d_in[8];
    const float* eb2 = (const float*)d_in[9];
    const float* cw1 = (const float*)d_in[10];
    const float* cb1 = (const float*)d_in[11];
    const float* cw2 = (const float*)d_in[12];
    const float* cb2 = (const float*)d_in[13];
    float* out = (float*)d_out;

    __hip_bfloat16* ws = (__hip_bfloat16*)d_ws;
    pack_weights<<<WS_TOTAL / 256, 256, 0, stream>>>(nw2, ew2, cw1, cw2, ws);

    const int grid = 16 * (NXc / Pc);   // 8192 blocks
    lifting_mfma<<<grid, NTc, 0, stream>>>(u0, x, nw1, nb1, nb2, eb1, eb2, cb1, cb2,
                                           ew1, (const short8*)d_ws, out);
}